// Round 2
// baseline (103.906 us; speedup 1.0000x reference)
//
#include <hip/hip_runtime.h>
#include <math.h>

#define PH 7
#define PW 7
#define BB 4
#define HH 64
#define WW 64
#define CC 256
#define RR 128
#define CH4 (CC / 4)                   // 64 float4 per pixel
#define BINS_PER_IMG (RR * PH * PW)    // 6272
#define NROWBINS (BB * RR * PH)        // 3584 waves: one per (b, r, ph)
#define WPB 4                          // waves per block (256 threads)
#define NBLK (NROWBINS / WPB)          // 896 blocks
#define BLK_PER_SLOT (NBLK / 8)        // 112 per xcd slot

typedef float f4 __attribute__((ext_vector_type(4)));

__device__ __forceinline__ f4 max4(f4 a, f4 b) {
    f4 r;
    r.x = fmaxf(a.x, b.x); r.y = fmaxf(a.y, b.y);
    r.z = fmaxf(a.z, b.z); r.w = fmaxf(a.w, b.w);
    return r;
}

// v3: one wave per (roi, bin-row ph) -> 3584 waves (was 25088 per-bin waves).
// R1 post-mortem: deeper per-wave MLP (ping-pong) was NEUTRAL -> the limiter
// is per-wave overhead/churn, not in-flight depth. Each wave now amortizes
// the serial prologue (global roi load ~200-900cyc + decode + runtime magic-
// divide setup ~30 instr) over 7 bins, and its 7 bins cover the contiguous
// pixel range [hs,he) x [w0,w0+rw) -> raster-ordered streaming reads.
// Lane l = channels 4l..4l+3; each pixel load = 1KB coalesced wave txn via
// SGPR base + 32-bit voffset. Flat p -> (row,col) in bin via 16-bit magic
// divide (exact: p <= ~121, wbin <= 11). Tail clamp re-loads pixel npix-1:
// L1-hit, idempotent under max. XCD swizzle: image b -> xcds {2b,2b+1} keeps
// its 4.2MB fm slice hot in one L2 pair (R2 evidence: FETCH 50->12MB).
__global__ __launch_bounds__(256) void ROIPoolingLayer_62079457296467_kernel(
    const float* __restrict__ fm, const float* __restrict__ rois,
    float* __restrict__ out)
{
    const int wave = threadIdx.x >> 6;
    const int lane = threadIdx.x & 63;

    // ---- XCD swizzle: 896 blocks = 8 xcds x 112; image b -> xcds {2b,2b+1}
    const int bid   = blockIdx.x;
    const int xcd   = bid & 7;
    const int slot  = bid >> 3;                        // 0..111
    const int b     = xcd >> 1;                        // image 0..3
    const int blkin = (xcd & 1) * BLK_PER_SLOT + slot; // 0..223 in image
    const int local = blkin * WPB + wave;              // 0..895 = r*PH + ph
    const int r     = local / PH;
    const int ph    = local - r * PH;
    const int br    = b * RR + r;

    // ---- ROI decode (reference fp32 semantics, truncating casts) ----
    const f4 roi = ((const f4*)rois)[br];
    const int h0 = (int)floorf((float)HH * roi.x);
    const int w0 = (int)floorf((float)WW * roi.y);
    const int h1 = (int)floorf((float)HH * roi.z);
    const int w1 = (int)floorf((float)WW * roi.w);
    const int rh = h1 - h0;
    const int rw = w1 - w0;
    const int hstep = max(rh / PH, 1);
    const int wstep = max(rw / PW, 1);

    // Bin-row window [hs,he); last row-bin extends to region end.
    int hs = h0 + ph * hstep;
    int he = (ph == PH - 1) ? (h0 + rh) : (hs + hstep);
    he = min(he, h0 + rh);  he = min(he, HH);
    const int hbin = he - hs;

    // Column geometry: interior bins have wbin = wstep; last bin extends.
    int wbin6 = rw - (PW - 1) * wstep;                 // >= wstep >= 1
    wbin6 = min(wbin6, WW - (w0 + (PW - 1) * wstep));  // safety clamp
    // magic divides, once per wave (was once per bin-wave):
    const unsigned m_int = (65536u + (unsigned)wstep - 1) / (unsigned)wstep;
    const unsigned m_6   = (65536u + (unsigned)wbin6 - 1) / (unsigned)wbin6;

    const int rowbase = (b * HH + hs) * WW;            // pixel idx of (hs, 0)

    for (int pw = 0; pw < PW; ++pw) {
        const int      ws   = w0 + pw * wstep;
        const int      wbin = (pw == PW - 1) ? wbin6 : wstep;
        const unsigned m    = (pw == PW - 1) ? m_6 : m_int;
        const int      npix = hbin * wbin;

        // wave-uniform base (SGPR); per-lane offset is 32-bit
        const f4* __restrict__ bp = (const f4*)fm + (size_t)(rowbase + ws) * CH4;

        f4 acc = (f4){-INFINITY, -INFINITY, -INFINITY, -INFINITY};

        if (npix > 0) {
            f4 bufA[8], bufB[8];

#define LOADR(buf, p0)                                                  \
            _Pragma("unroll")                                           \
            for (int k = 0; k < 8; ++k) {                               \
                const int pk = min((p0) + k, npix - 1);                 \
                const int q  = (int)(((unsigned)pk * m) >> 16);         \
                const int w  = pk - q * wbin;                           \
                buf[k] = bp[(q * WW + w) * CH4 + lane];                 \
            }
#define CONS(buf)                                                       \
            {                                                           \
                f4 m0 = max4(buf[0], buf[1]);                           \
                f4 m1 = max4(buf[2], buf[3]);                           \
                f4 m2 = max4(buf[4], buf[5]);                           \
                f4 m3 = max4(buf[6], buf[7]);                           \
                acc = max4(acc, max4(max4(m0, m1), max4(m2, m3)));      \
            }

            const int rounds = (npix + 7) >> 3;   // <= 16
            LOADR(bufA, 0)
            int t = 1;
            for (; t + 1 < rounds; t += 2) {      // 16 loads in flight
                LOADR(bufB, t * 8)
                CONS(bufA)
                LOADR(bufA, (t + 1) * 8)
                CONS(bufB)
            }
            if (t < rounds) {
                LOADR(bufB, t * 8)
                CONS(bufA)
                CONS(bufB)
            } else {
                CONS(bufA)
            }
#undef LOADR
#undef CONS
        }

        // Output (b,r,ph,pw,C); non-temporal (never re-read).
        const size_t gbin = (size_t)(br * PH + ph) * PW + pw;
        __builtin_nontemporal_store(acc, (f4*)out + gbin * CH4 + lane);
    }
}

extern "C" void kernel_launch(void* const* d_in, const int* in_sizes, int n_in,
                              void* d_out, int out_size, void* d_ws, size_t ws_size,
                              hipStream_t stream) {
    const float* fm   = (const float*)d_in[0];
    const float* rois = (const float*)d_in[1];
    float* out        = (float*)d_out;
    ROIPoolingLayer_62079457296467_kernel<<<NBLK, 256, 0, stream>>>(fm, rois, out);
}

// Round 3
// 88.449 us; speedup vs baseline: 1.1748x; 1.1748x over previous
//
#include <hip/hip_runtime.h>
#include <math.h>

#define PH 7
#define PW 7
#define BB 4
#define HH 64
#define WW 64
#define CC 256
#define RR 128
#define CH4 (CC / 4)                   // 64 float4 per pixel
#define BINS_PER_IMG (RR * PH * PW)    // 6272
#define NBINS (BB * BINS_PER_IMG)      // 25088
#define NBLK (NBINS / 4)               // 6272 blocks, 4 waves each
#define BLK_PER_IMG (NBLK / 8)         // 784 per xcd slot

// workspace pyramid tables, offsets in f4 (16B) units; total 20 MB << ws
#define P2_OFF 0                              // [BB][32][32] px: 2x2 max
#define C2_OFF (BB * 32 * 32 * CH4)           // [BB][32][64] px: 2x1 (row-pair) max
#define R2_OFF (C2_OFF + BB * 32 * 64 * CH4)  // [BB][64][32] px: 1x2 (col-pair) max

typedef float f4 __attribute__((ext_vector_type(4)));

__device__ __forceinline__ f4 max4(f4 a, f4 b) {
    f4 r;
    r.x = fmaxf(a.x, b.x); r.y = fmaxf(a.y, b.y);
    r.z = fmaxf(a.z, b.z); r.w = fmaxf(a.w, b.w);
    return r;
}

// v4 theory: per-CU L1 miss-service rate (~3.8 cyc/line) is the wall -- every
// 64B line is a compulsory miss (no reuse within a CU), 23.7K misses/CU = 44us.
// Fix = touch fewer lines: one-time 2x2 max pre-pool (P2) + half-pools (C2 row-
// pair, R2 col-pair) in d_ws; each bin = coarse interior + parity edges + corners.
// Avg bin 4x4: 16 pixel loads -> ~6 table loads (2.4x fewer lines). Build pass
// reads fm once (16 MB, ~3us). Main keeps v1's proven structure: wave per bin,
// lane = 4 channels (1KB coalesced txn), XCD swizzle image b -> xcds {2b,2b+1}.

__global__ __launch_bounds__(256) void roi_build_pyr(
    const float* __restrict__ fm, float* __restrict__ tab)
{
    const int wave = threadIdx.x >> 6;
    const int lane = threadIdx.x & 63;
    const int bid  = blockIdx.x;            // 1024 blocks
    const int xcd  = bid & 7;
    const int slot = bid >> 3;              // 0..127
    const int b    = xcd >> 1;              // image -> same xcd-pair as main
    const int ci   = (xcd & 1) * 512 + slot * 4 + wave;   // cell 0..1023
    const int h2   = ci >> 5;
    const int w2   = ci & 31;

    const f4* fp = (const f4*)fm + ((size_t)(b * HH + 2 * h2) * WW + 2 * w2) * CH4 + lane;
    const f4 v00 = fp[0];
    const f4 v01 = fp[CH4];
    const f4 v10 = fp[WW * CH4];
    const f4 v11 = fp[WW * CH4 + CH4];
    const f4 r0 = max4(v00, v01);           // R2 row 2h2   (col-pair w2)
    const f4 r1 = max4(v10, v11);           // R2 row 2h2+1
    const f4 c0 = max4(v00, v10);           // C2 col 2w2   (row-pair h2)
    const f4 c1 = max4(v01, v11);           // C2 col 2w2+1
    const f4 p  = max4(r0, r1);             // P2

    f4* P2 = (f4*)tab + P2_OFF;
    f4* C2 = (f4*)tab + C2_OFF;
    f4* R2 = (f4*)tab + R2_OFF;
    P2[((b * 32 + h2) * 32 + w2) * CH4 + lane]          = p;
    C2[((b * 32 + h2) * 64 + 2 * w2) * CH4 + lane]      = c0;
    C2[((b * 32 + h2) * 64 + 2 * w2 + 1) * CH4 + lane]  = c1;
    R2[((b * 64 + 2 * h2) * 32 + w2) * CH4 + lane]      = r0;
    R2[((b * 64 + 2 * h2 + 1) * 32 + w2) * CH4 + lane]  = r1;
}

__global__ __launch_bounds__(256) void ROIPoolingLayer_62079457296467_kernel(
    const float* __restrict__ fm, const float* __restrict__ rois,
    const float* __restrict__ tab, float* __restrict__ out)
{
    const int wave = threadIdx.x >> 6;
    const int lane = threadIdx.x & 63;

    // ---- XCD swizzle: 6272 blocks = 8 xcds x 784; image b -> xcds {2b,2b+1}
    const int bid   = blockIdx.x;
    const int xcd   = bid & 7;
    const int slot  = bid >> 3;                     // 0..783
    const int b     = xcd >> 1;
    const int blkin = (xcd & 1) * BLK_PER_IMG + slot;
    const int local = blkin * 4 + wave;             // r*49 + bin
    const int r     = local / (PH * PW);
    const int bin   = local - r * (PH * PW);
    const int ph    = bin / PW;
    const int pw    = bin - ph * PW;
    const int br    = b * RR + r;

    // ---- ROI decode (reference fp32 semantics, truncating casts) ----
    const f4 roi = ((const f4*)rois)[br];
    const int h0 = (int)floorf((float)HH * roi.x);
    const int w0 = (int)floorf((float)WW * roi.y);
    const int h1 = (int)floorf((float)HH * roi.z);
    const int w1 = (int)floorf((float)WW * roi.w);
    const int rh = h1 - h0;
    const int rw = w1 - w0;
    const int hstep = max(rh / PH, 1);
    const int wstep = max(rw / PW, 1);

    // Bin window [hs,he) x [cs,ce); last bin extends to region end.
    int hs = h0 + ph * hstep;
    int he = (ph == PH - 1) ? (h0 + rh) : (hs + hstep);
    he = min(he, h0 + rh);  he = min(he, HH);
    int cs = w0 + pw * wstep;
    int ce = (pw == PW - 1) ? (w0 + rw) : (cs + wstep);
    ce = min(ce, w0 + rw);  ce = min(ce, WW);
    // hbin,wbin >= 1 always (region >= pooled grid by construction)

    // ---- exact 2-level decomposition (all flags/bounds wave-uniform) ----
    const int h2a = (hs + 1) >> 1, h2b = he >> 1;   // coarse row-pairs
    const int w2a = (cs + 1) >> 1, w2b = ce >> 1;   // coarse col-pairs
    const int hA = h2b - h2a, wA = w2b - w2a;
    const int ft = hs & 1, fb = he & 1;             // fine rows: hs, he-1
    const int fl = cs & 1, fr = ce & 1;             // fine cols: cs, ce-1

    const f4* P2 = (const f4*)tab + P2_OFF;
    const f4* C2 = (const f4*)tab + C2_OFF;
    const f4* R2 = (const f4*)tab + R2_OFF;

    f4 acc = (f4){-INFINITY, -INFINITY, -INFINITY, -INFINITY};

    // A: coarse interior from P2 (avg ~2.25 loads), batched by 4
    const int nA = hA * wA;
    if (nA > 0) {
        const unsigned m = (65536u + (unsigned)wA - 1) / (unsigned)wA;
        const f4* bp = P2 + ((size_t)(b * 32 + h2a) * 32 + w2a) * CH4 + lane;
        for (int p = 0; p < nA; p += 4) {
            f4 v[4];
#pragma unroll
            for (int k = 0; k < 4; ++k) {
                const int pk = min(p + k, nA - 1);          // clamp: dup = L1 hit
                const int q  = (int)(((unsigned)pk * m) >> 16);
                const int w  = pk - q * wA;
                v[k] = bp[(q * 32 + w) * CH4];
            }
#pragma unroll
            for (int k = 0; k < 4; ++k) acc = max4(acc, v[k]);
        }
    }

    // B: fine rows via R2 (col-pairs)
    if (ft) {
        const f4* rp = R2 + ((size_t)(b * 64 + hs) * 32 + w2a) * CH4 + lane;
        for (int i = 0; i < wA; ++i) acc = max4(acc, rp[i * CH4]);
    }
    if (fb) {
        const f4* rp = R2 + ((size_t)(b * 64 + (he - 1)) * 32 + w2a) * CH4 + lane;
        for (int i = 0; i < wA; ++i) acc = max4(acc, rp[i * CH4]);
    }

    // C: fine cols via C2 (row-pairs); h2-stride = 64 px
    if (fl) {
        const f4* cp = C2 + ((size_t)(b * 32 + h2a) * 64 + cs) * CH4 + lane;
        for (int i = 0; i < hA; ++i) acc = max4(acc, cp[(size_t)i * 64 * CH4]);
    }
    if (fr) {
        const f4* cp = C2 + ((size_t)(b * 32 + h2a) * 64 + (ce - 1)) * CH4 + lane;
        for (int i = 0; i < hA; ++i) acc = max4(acc, cp[(size_t)i * 64 * CH4]);
    }

    // D: fine corners from fm
    const f4* fb4 = (const f4*)fm + (size_t)b * HH * WW * CH4 + lane;
    if (ft & fl) acc = max4(acc, fb4[(hs * WW + cs) * CH4]);
    if (ft & fr) acc = max4(acc, fb4[(hs * WW + (ce - 1)) * CH4]);
    if (fb & fl) acc = max4(acc, fb4[((he - 1) * WW + cs) * CH4]);
    if (fb & fr) acc = max4(acc, fb4[((he - 1) * WW + (ce - 1)) * CH4]);

    // Output (b,r,ph,pw,C); non-temporal (never re-read).
    const size_t gbin = (size_t)b * BINS_PER_IMG + local;
    __builtin_nontemporal_store(acc, (f4*)out + gbin * CH4 + lane);
}

extern "C" void kernel_launch(void* const* d_in, const int* in_sizes, int n_in,
                              void* d_out, int out_size, void* d_ws, size_t ws_size,
                              hipStream_t stream) {
    const float* fm   = (const float*)d_in[0];
    const float* rois = (const float*)d_in[1];
    float* out        = (float*)d_out;
    float* tab        = (float*)d_ws;
    roi_build_pyr<<<1024, 256, 0, stream>>>(fm, tab);
    ROIPoolingLayer_62079457296467_kernel<<<NBLK, 256, 0, stream>>>(fm, rois, tab, out);
}